// Round 1
// baseline (692.437 us; speedup 1.0000x reference)
//
#include <hip/hip_runtime.h>

typedef __attribute__((ext_vector_type(8))) short bf16x8;
typedef __attribute__((ext_vector_type(8))) unsigned short ushort8;
typedef __attribute__((ext_vector_type(4))) float f32x4;

__device__ inline unsigned short f2bf(float f){
  unsigned u = __builtin_bit_cast(unsigned, f);
  return (unsigned short)((u + 0x7fffu + ((u>>16)&1u)) >> 16);
}
__device__ inline float bf2f(unsigned short h){
  return __builtin_bit_cast(float, (unsigned)h << 16);
}

__device__ inline void gll16(const void* g, void* l){
  __builtin_amdgcn_global_load_lds((const __attribute__((address_space(1))) void*)g,
                                   (__attribute__((address_space(3))) void*)l, 16, 0, 0);
}

// ---------------- LayerNorm: x (f32) -> x_norm bf16 into A3[:, 0:256] (row stride 512)
__global__ __launch_bounds__(256) void k_ln(const float* __restrict__ x,
                                            const float* __restrict__ g,
                                            unsigned short* __restrict__ A3){
  int r = blockIdx.x, c = threadIdx.x;
  float v = x[(size_t)r*256 + c];
  float s = v, s2 = v*v;
  #pragma unroll
  for (int m=32; m>=1; m>>=1){ s += __shfl_xor(s, m, 64); s2 += __shfl_xor(s2, m, 64); }
  __shared__ float rs[4], rs2[4];
  int wid = c>>6, lane = c&63;
  if (lane==0){ rs[wid]=s; rs2[wid]=s2; }
  __syncthreads();
  float ts  = rs[0]+rs[1]+rs[2]+rs[3];
  float ts2 = rs2[0]+rs2[1]+rs2[2]+rs2[3];
  float mu  = ts*(1.f/256.f);
  float var = ts2*(1.f/256.f) - mu*mu;
  float xn = (v-mu)*rsqrtf(var + 1e-6f)*g[c];
  A3[(size_t)r*512 + c] = f2bf(xn);
}

// ---------------- column means of x_norm per image (two-stage, deterministic)
__global__ __launch_bounds__(256) void k_cm1(const unsigned short* __restrict__ A3,
                                             float* __restrict__ psum){
  int blk = blockIdx.x;        // b*64 + chunk
  int c = threadIdx.x;
  const unsigned short* base = A3 + (size_t)blk*256*512;
  float s = 0.f;
  for (int p=0;p<256;p++) s += bf2f(base[(size_t)p*512 + c]);
  psum[blk*256 + c] = s;
}
__global__ __launch_bounds__(256) void k_cm2(const float* __restrict__ psum,
                                             float* __restrict__ m){
  int b = blockIdx.x, c = threadIdx.x;
  float s = 0.f;
  for (int ch=0; ch<64; ch++) s += psum[(b*64+ch)*256 + c];
  m[b*256 + c] = s*(1.f/16384.f);
}

// ---------------- weight transposes to bf16 (Bt layout [N][K])
__global__ __launch_bounds__(256) void k_prep_nt(const float* __restrict__ W,
                                                 unsigned short* __restrict__ WT, int K){
  int idx = blockIdx.x*256 + threadIdx.x;   // over 256*K
  int j = idx / K, k = idx - j*K;
  WT[idx] = f2bf(W[(size_t)k*256 + j]);
}

// WT_all: [11][256 n][256 k]: segs 0..7 = w_geo_local blocks, 8..9 = -2*Wi_global[s]
__global__ __launch_bounds__(256) void k_prep_geoT(const float* __restrict__ wl,
                                                   const float* __restrict__ wg,
                                                   unsigned short* __restrict__ WT){
  int idx = blockIdx.x*256 + threadIdx.x;   // over 10*65536
  int sg = idx >> 16, rem = idx & 65535;
  int j = rem >> 8, k = rem & 255;
  float v;
  if (sg < 8) v = wl[(size_t)(sg*256 + k)*256 + j];
  else        v = -2.f * wg[(size_t)((sg-8)*2*256 + k)*256 + j];
  WT[idx] = f2bf(v);
}

// W_eff[b][c,j] = sum_s m[(c-s)%C](Wi+Ww)[s][c,j] + m[(c+s)%C](Wi-Ww)[s][(c+s)%C,j]
// stored transposed: WEFFT[b][j][c]
__global__ __launch_bounds__(256) void k_prep_weff(const float* __restrict__ wg,
                                                   const float* __restrict__ m,
                                                   unsigned short* __restrict__ WT){
  int b = blockIdx.x >> 8, c = blockIdx.x & 255, j = threadIdx.x;
  float acc = 0.f;
  #pragma unroll
  for (int si=0; si<2; ++si){
    int s = si+1;
    int cm = (c - s) & 255, cp = (c + s) & 255;
    float wi_c  = wg[(size_t)((2*si)*256 + c)*256 + j];
    float ww_c  = wg[(size_t)((2*si+1)*256 + c)*256 + j];
    float wi_cp = wg[(size_t)((2*si)*256 + cp)*256 + j];
    float ww_cp = wg[(size_t)((2*si+1)*256 + cp)*256 + j];
    acc += m[b*256+cm]*(wi_c+ww_c) + m[b*256+cp]*(wi_cp-ww_cp);
  }
  WT[(size_t)b*65536 + (size_t)j*256 + c] = f2bf(acc);
}

// ---------------- depthwise 3x3 conv 1
__global__ __launch_bounds__(256) void k_dw1(const unsigned short* __restrict__ A3,
                                             const float* __restrict__ dw,
                                             unsigned short* __restrict__ outp){
  int r = blockIdx.x, c = threadIdx.x;
  int wq = r & 127, h = (r>>7)&127, b = r>>14;
  float acc = 0.f;
  #pragma unroll
  for (int kh=0;kh<3;kh++){
    int h2 = h+kh-1; if ((unsigned)h2 >= 128u) continue;
    #pragma unroll
    for (int kw=0;kw<3;kw++){
      int w2 = wq+kw-1; if ((unsigned)w2 >= 128u) continue;
      acc += bf2f(A3[((size_t)((b<<14)+(h2<<7)+w2))*512 + c]) * dw[(kh*3+kw)*256 + c];
    }
  }
  outp[(size_t)r*256 + c] = f2bf(acc);
}

// ---------------- depthwise conv 2 + BN + SiLU - z_det
__global__ __launch_bounds__(256) void k_dw2(const unsigned short* __restrict__ tin,
                                             const float* __restrict__ dw,
                                             const float* __restrict__ bg,
                                             const float* __restrict__ bm_,
                                             const float* __restrict__ bv,
                                             const unsigned short* __restrict__ zdet,
                                             unsigned short* __restrict__ zcx){
  int r = blockIdx.x, c = threadIdx.x;
  int wq = r & 127, h = (r>>7)&127, b = r>>14;
  float acc = 0.f;
  #pragma unroll
  for (int kh=0;kh<3;kh++){
    int h2 = h+kh-1; if ((unsigned)h2 >= 128u) continue;
    #pragma unroll
    for (int kw=0;kw<3;kw++){
      int w2 = wq+kw-1; if ((unsigned)w2 >= 128u) continue;
      acc += bf2f(tin[((size_t)((b<<14)+(h2<<7)+w2))*256 + c]) * dw[(kh*3+kw)*256 + c];
    }
  }
  float t = (acc - bm_[c]) * rsqrtf(bv[c] + 1e-3f) * bg[c];
  t = t / (1.f + __expf(-t));
  float z = t - bf2f(zdet[(size_t)r*256 + c]);
  zcx[(size_t)r*256 + c] = f2bf(z);
}

// ---------------- generic MFMA GEMM: C = A[M,K] * (Bt[N,K])^T, 128x128 tile, BK=64
// EPI 0: write bf16 (zdet).  EPI 1: gate sigmoid + final mix, writes f32 out.
template<int EPI>
__global__ __launch_bounds__(256) void k_gemm(const unsigned short* __restrict__ A, int lda,
                                              const unsigned short* __restrict__ Bt, int K,
                                              unsigned short* __restrict__ outbf,
                                              const float* __restrict__ xin,
                                              const unsigned short* __restrict__ A3,
                                              const float* __restrict__ gls,
                                              float* __restrict__ out){
  __shared__ unsigned short As[128*64];
  __shared__ unsigned short Bs[128*64];
  const int tid=threadIdx.x, lane=tid&63, wid=tid>>6;
  const int bm = blockIdx.x*128, bn = blockIdx.y*128;
  const int wr = wid>>1, wc = wid&1;
  f32x4 acc[4][4] = {};
  const int nk = K>>6;
  for (int t=0; t<nk; ++t){
    int k0 = t*64;
    #pragma unroll
    for (int i=0;i<4;i++){
      int q = wid*4 + i;
      int row = q*8 + (lane>>3), kc = (lane&7)*8;
      gll16(A  + (size_t)(bm+row)*lda + k0 + kc, &As[q*512]);
      gll16(Bt + (size_t)(bn+row)*K   + k0 + kc, &Bs[q*512]);
    }
    __syncthreads();
    #pragma unroll
    for (int kk=0; kk<2; ++kk){
      bf16x8 af[4], bfr[4];
      #pragma unroll
      for (int i=0;i<4;i++){
        int rl = wr*64 + i*16 + (lane&15);
        int kc = kk*32 + (lane>>4)*8;
        af[i]  = *(const bf16x8*)&As[rl*64 + kc];
        int cl = wc*64 + i*16 + (lane&15);
        bfr[i] = *(const bf16x8*)&Bs[cl*64 + kc];
      }
      #pragma unroll
      for (int i=0;i<4;i++)
        #pragma unroll
        for (int j=0;j<4;j++)
          acc[i][j] = __builtin_amdgcn_mfma_f32_16x16x32_bf16(af[i], bfr[j], acc[i][j], 0,0,0);
    }
    __syncthreads();
  }
  #pragma unroll
  for (int i=0;i<4;i++)
    #pragma unroll
    for (int j=0;j<4;j++)
      #pragma unroll
      for (int r=0;r<4;r++){
        int row = bm + wr*64 + i*16 + (lane>>4)*4 + r;
        int col = bn + wc*64 + j*16 + (lane&15);
        float v = acc[i][j][r];
        if constexpr (EPI==0){
          outbf[(size_t)row*256 + col] = f2bf(v);
        } else {
          float alpha = 1.f/(1.f+__expf(-v));
          float xnv = bf2f(A3[(size_t)row*512 + col]);
          float gfv = bf2f(A3[(size_t)row*512 + 256 + col]);
          float sl = xnv/(1.f+__expf(-xnv));
          out[(size_t)row*256 + col] = xin[(size_t)row*256 + col] + (sl + alpha*gfv)*gls[col];
        }
      }
}

// ---------------- fused geo GEMM: K=2816 (11 segs x 256), A generated in registers
template<int S>
__device__ __attribute__((always_inline)) ushort8 shsel(ushort8 hi, ushort8 lo){
  ushort8 r;
  if constexpr (S==0) return hi;
  #pragma unroll
  for (int e=0;e<8;e++) r[e] = (e<S) ? lo[8-S+e] : hi[e-S];
  return r;
}

template<int SEG>
__device__ __attribute__((always_inline)) bf16x8 gen_af(const float* fzd, const float* fzc,
      ushort8 zdh, ushort8 zdl, ushort8 zch, ushort8 zcl){
  bf16x8 r;
  if constexpr (SEG==10){
    r = __builtin_bit_cast(bf16x8, zdh);
  } else if constexpr (SEG>=8){
    constexpr int S = SEG-7;
    ushort8 zds = shsel<S>(zdh, zdl);
    #pragma unroll
    for (int e=0;e<8;e++) r[e] = (short)f2bf(fzd[e]*bf2f(zds[e]));
  } else {
    constexpr int S = 1 << (SEG>>1);
    constexpr bool W = SEG & 1;
    ushort8 zds = shsel<S>(zdh, zdl);
    ushort8 zcs = shsel<S>(zch, zcl);
    #pragma unroll
    for (int e=0;e<8;e++){
      float p = fzd[e]*bf2f(zcs[e]);
      float q = bf2f(zds[e])*fzc[e];
      r[e] = (short)f2bf(W ? (p-q) : (p+q));
    }
  }
  return r;
}

__global__ __launch_bounds__(512) void k_geo(const unsigned short* __restrict__ zd,
                                             const unsigned short* __restrict__ zc,
                                             const unsigned short* __restrict__ WT_all,
                                             const unsigned short* __restrict__ WeffT,
                                             unsigned short* __restrict__ A3){
  __shared__ unsigned short Bs[2][128*40];   // padded rows (40 elems) to spread banks
  const int tid = threadIdx.x, lane = tid&63, wid = tid>>6;
  const int bm = blockIdx.x*128, bn = blockIdx.y*128;
  const int img = blockIdx.x >> 7;           // 128 row-blocks per image
  const int wr = wid>>1, wc = wid&1;
  f32x4 acc[2][4] = {};

  const int sn = tid>>2, sko = (tid&3)*8;    // staging: thread -> (n, k-offset)
  auto srcptr = [&](int it)->const unsigned short*{
    int k32 = it/11, seg = it - k32*11;
    const unsigned short* Wb = (seg<10) ? (WT_all + (size_t)seg*65536)
                                        : (WeffT + (size_t)img*65536);
    return Wb + (size_t)(bn + sn)*256 + k32*32 + sko;
  };
  ushort8 sreg = *(const ushort8*)srcptr(0);
  *(ushort8*)&Bs[0][sn*40 + sko] = sreg;

  ushort8 zdh[2], zdl[2], zch[2], zcl[2];
  float fzd[2][8], fzc[2][8];
  ushort8 nreg;
  int buf = 0;
  for (int it=0; it<88; ++it){
    int k32 = it/11, seg = it - k32*11;
    if (seg==0){
      #pragma unroll
      for (int rg=0; rg<2; ++rg){
        int m = bm + wr*32 + rg*16 + (lane&15);
        int c = k32*32 + (lane>>4)*8;
        const unsigned short* zr = zd + (size_t)m*256;
        const unsigned short* cr = zc + (size_t)m*256;
        zdh[rg] = *(const ushort8*)(zr + c);
        zdl[rg] = *(const ushort8*)(zr + ((c-8)&255));
        zch[rg] = *(const ushort8*)(cr + c);
        zcl[rg] = *(const ushort8*)(cr + ((c-8)&255));
        #pragma unroll
        for (int e=0;e<8;e++){ fzd[rg][e]=bf2f(zdh[rg][e]); fzc[rg][e]=bf2f(zch[rg][e]); }
      }
    }
    if (it+1 < 88) nreg = *(const ushort8*)srcptr(it+1);
    __syncthreads();
    bf16x8 af[2];
    #define GCASE(NN) case NN: \
      af[0]=gen_af<NN>(fzd[0],fzc[0],zdh[0],zdl[0],zch[0],zcl[0]); \
      af[1]=gen_af<NN>(fzd[1],fzc[1],zdh[1],zdl[1],zch[1],zcl[1]); break;
    switch(seg){ GCASE(0) GCASE(1) GCASE(2) GCASE(3) GCASE(4) GCASE(5)
                 GCASE(6) GCASE(7) GCASE(8) GCASE(9) GCASE(10) }
    #undef GCASE
    bf16x8 bfr[4];
    #pragma unroll
    for (int fj=0; fj<4; ++fj){
      int n = wc*64 + fj*16 + (lane&15);
      bfr[fj] = *(const bf16x8*)&Bs[buf][n*40 + (lane>>4)*8];
    }
    #pragma unroll
    for (int rg=0; rg<2; ++rg)
      #pragma unroll
      for (int fj=0; fj<4; ++fj)
        acc[rg][fj] = __builtin_amdgcn_mfma_f32_16x16x32_bf16(af[rg], bfr[fj], acc[rg][fj], 0,0,0);
    if (it+1 < 88){
      *(ushort8*)&Bs[buf^1][sn*40 + sko] = nreg;
      buf ^= 1;
    }
  }
  #pragma unroll
  for (int rg=0; rg<2; ++rg)
    #pragma unroll
    for (int fj=0; fj<4; ++fj)
      #pragma unroll
      for (int r=0; r<4; ++r){
        int row = bm + wr*32 + rg*16 + (lane>>4)*4 + r;
        int col = bn + wc*64 + fj*16 + (lane&15);
        A3[(size_t)row*512 + 256 + col] = f2bf(acc[rg][fj][r]);
      }
}

extern "C" void kernel_launch(void* const* d_in, const int* in_sizes, int n_in,
                              void* d_out, int out_size, void* d_ws, size_t ws_size,
                              hipStream_t stream){
  (void)in_sizes; (void)n_in; (void)out_size; (void)ws_size;
  const float* x    = (const float*)d_in[0];
  const float* lng  = (const float*)d_in[1];
  const float* wdet = (const float*)d_in[2];
  const float* dw1  = (const float*)d_in[3];
  const float* dw2  = (const float*)d_in[4];
  const float* bng  = (const float*)d_in[5];
  const float* bnm  = (const float*)d_in[6];
  const float* bnv  = (const float*)d_in[7];
  const float* wloc = (const float*)d_in[8];
  const float* wglo = (const float*)d_in[9];
  const float* wgat = (const float*)d_in[10];
  const float* gls  = (const float*)d_in[11];
  float* out = (float*)d_out;
  char* ws = (char*)d_ws;

  unsigned short* A3     = (unsigned short*)(ws);                 // 64 MB [65536][512]
  unsigned short* ZDET   = (unsigned short*)(ws + 67108864);      // 32 MB
  unsigned short* TMP    = (unsigned short*)(ws + 100663296);     // 32 MB
  unsigned short* ZCX    = (unsigned short*)(ws + 134217728);     // 32 MB
  unsigned short* WTALL  = (unsigned short*)(ws + 167772160);     // 1.44 MB [11][256][256]
  unsigned short* WEFFT  = (unsigned short*)(ws + 169213952);     // 0.5 MB [4][256][256]
  unsigned short* WDETT  = (unsigned short*)(ws + 169738240);     // 128 KB
  unsigned short* WGATET = (unsigned short*)(ws + 169869312);     // 256 KB
  float* PSUM  = (float*)(ws + 170131456);                        // 256 KB
  float* MMEAN = (float*)(ws + 170393600);                        // 4 KB

  k_ln<<<65536, 256, 0, stream>>>(x, lng, A3);
  k_cm1<<<256, 256, 0, stream>>>(A3, PSUM);
  k_cm2<<<4, 256, 0, stream>>>(PSUM, MMEAN);
  k_prep_nt<<<256, 256, 0, stream>>>(wdet, WDETT, 256);
  k_prep_nt<<<512, 256, 0, stream>>>(wgat, WGATET, 512);
  k_prep_geoT<<<2560, 256, 0, stream>>>(wloc, wglo, WTALL);
  k_prep_weff<<<1024, 256, 0, stream>>>(wglo, MMEAN, WEFFT);
  k_gemm<0><<<dim3(512,2), 256, 0, stream>>>(A3, 512, WDETT, 256, ZDET,
                                             nullptr, nullptr, nullptr, nullptr);
  k_dw1<<<65536, 256, 0, stream>>>(A3, dw1, TMP);
  k_dw2<<<65536, 256, 0, stream>>>(TMP, dw2, bng, bnm, bnv, ZDET, ZCX);
  k_geo<<<dim3(512,2), 512, 0, stream>>>(ZDET, ZCX, WTALL, WEFFT, A3);
  k_gemm<1><<<dim3(512,2), 256, 0, stream>>>(A3, 512, WGATET, 512, nullptr,
                                             x, A3, gls, out);
}

// Round 2
// 514.952 us; speedup vs baseline: 1.3447x; 1.3447x over previous
//
#include <hip/hip_runtime.h>

typedef __attribute__((ext_vector_type(8))) short bf16x8;
typedef __attribute__((ext_vector_type(8))) unsigned short ushort8;
typedef __attribute__((ext_vector_type(4))) float f32x4;
typedef __attribute__((ext_vector_type(4))) unsigned uint4v;

__device__ inline unsigned short f2bf(float f){
  unsigned u = __builtin_bit_cast(unsigned, f);
  return (unsigned short)((u + 0x7fffu + ((u>>16)&1u)) >> 16);
}
__device__ inline float bf2f(unsigned short h){
  return __builtin_bit_cast(float, (unsigned)h << 16);
}

__device__ inline void gll16(const void* g, void* l){
  __builtin_amdgcn_global_load_lds((const __attribute__((address_space(1))) void*)g,
                                   (__attribute__((address_space(3))) void*)l, 16, 0, 0);
}

// ---------------- LayerNorm: x (f32) -> x_norm bf16 into A3[:, 0:256] (row stride 512)
__global__ __launch_bounds__(256) void k_ln(const float* __restrict__ x,
                                            const float* __restrict__ g,
                                            unsigned short* __restrict__ A3){
  int r = blockIdx.x, c = threadIdx.x;
  float v = x[(size_t)r*256 + c];
  float s = v, s2 = v*v;
  #pragma unroll
  for (int m=32; m>=1; m>>=1){ s += __shfl_xor(s, m, 64); s2 += __shfl_xor(s2, m, 64); }
  __shared__ float rs[4], rs2[4];
  int wid = c>>6, lane = c&63;
  if (lane==0){ rs[wid]=s; rs2[wid]=s2; }
  __syncthreads();
  float ts  = rs[0]+rs[1]+rs[2]+rs[3];
  float ts2 = rs2[0]+rs2[1]+rs2[2]+rs2[3];
  float mu  = ts*(1.f/256.f);
  float var = ts2*(1.f/256.f) - mu*mu;
  float xn = (v-mu)*rsqrtf(var + 1e-6f)*g[c];
  A3[(size_t)r*512 + c] = f2bf(xn);
}

// ---------------- column means of x_norm per image (two-stage, deterministic)
__global__ __launch_bounds__(256) void k_cm1(const unsigned short* __restrict__ A3,
                                             float* __restrict__ psum){
  int blk = blockIdx.x;        // b*64 + chunk
  int c = threadIdx.x;
  const unsigned short* base = A3 + (size_t)blk*256*512;
  float s = 0.f;
  for (int p=0;p<256;p++) s += bf2f(base[(size_t)p*512 + c]);
  psum[blk*256 + c] = s;
}
__global__ __launch_bounds__(256) void k_cm2(const float* __restrict__ psum,
                                             float* __restrict__ m){
  int b = blockIdx.x, c = threadIdx.x;
  float s = 0.f;
  for (int ch=0; ch<64; ch++) s += psum[(b*64+ch)*256 + c];
  m[b*256 + c] = s*(1.f/16384.f);
}

// ---------------- weight transposes to bf16 (Bt layout [N][K])
__global__ __launch_bounds__(256) void k_prep_nt(const float* __restrict__ W,
                                                 unsigned short* __restrict__ WT, int K){
  int idx = blockIdx.x*256 + threadIdx.x;   // over 256*K
  int j = idx / K, k = idx - j*K;
  WT[idx] = f2bf(W[(size_t)k*256 + j]);
}

// WT_all: [10][256 n][256 k] reformulated weights:
// seg 2i   (t=+s): Wi_s + Ww_s               (feature zd[c]*zc[c-s])
// seg 2i+1 (t=-s): (Wi_s - Ww_s)[(k+s)%C,:]  (feature zd[c]*zc[c+s])
// seg 8+j: -2*Wi_global[j]                   (feature zd[c]*zd[c-s_j])
__global__ __launch_bounds__(256) void k_prep_geoT(const float* __restrict__ wl,
                                                   const float* __restrict__ wg,
                                                   unsigned short* __restrict__ WT){
  int idx = blockIdx.x*256 + threadIdx.x;   // over 10*65536
  int sg = idx >> 16, rem = idx & 65535;
  int j = rem >> 8, k = rem & 255;          // out [sg][n=j][k]
  float v;
  if (sg < 8){
    int si = sg >> 1, s = 1 << si;
    bool neg = sg & 1;
    int krow = neg ? ((k + s) & 255) : k;
    float wi = wl[(size_t)((2*si)*256 + krow)*256 + j];
    float ww = wl[(size_t)((2*si+1)*256 + krow)*256 + j];
    v = neg ? (wi - ww) : (wi + ww);
  } else {
    v = -2.f * wg[(size_t)((sg-8)*2*256 + k)*256 + j];
  }
  WT[idx] = f2bf(v);
}

// W_eff[b][c,j] = sum_s m[(c-s)%C](Wi+Ww)[s][c,j] + m[(c+s)%C](Wi-Ww)[s][(c+s)%C,j]
// stored transposed: WEFFT[b][j][c]
__global__ __launch_bounds__(256) void k_prep_weff(const float* __restrict__ wg,
                                                   const float* __restrict__ m,
                                                   unsigned short* __restrict__ WT){
  int b = blockIdx.x >> 8, c = blockIdx.x & 255, j = threadIdx.x;
  float acc = 0.f;
  #pragma unroll
  for (int si=0; si<2; ++si){
    int s = si+1;
    int cm = (c - s) & 255, cp = (c + s) & 255;
    float wi_c  = wg[(size_t)((2*si)*256 + c)*256 + j];
    float ww_c  = wg[(size_t)((2*si+1)*256 + c)*256 + j];
    float wi_cp = wg[(size_t)((2*si)*256 + cp)*256 + j];
    float ww_cp = wg[(size_t)((2*si+1)*256 + cp)*256 + j];
    acc += m[b*256+cm]*(wi_c+ww_c) + m[b*256+cp]*(wi_cp-ww_cp);
  }
  WT[(size_t)b*65536 + (size_t)j*256 + c] = f2bf(acc);
}

// ---------------- depthwise 3x3 conv 1
__global__ __launch_bounds__(256) void k_dw1(const unsigned short* __restrict__ A3,
                                             const float* __restrict__ dw,
                                             unsigned short* __restrict__ outp){
  int r = blockIdx.x, c = threadIdx.x;
  int wq = r & 127, h = (r>>7)&127, b = r>>14;
  float acc = 0.f;
  #pragma unroll
  for (int kh=0;kh<3;kh++){
    int h2 = h+kh-1; if ((unsigned)h2 >= 128u) continue;
    #pragma unroll
    for (int kw=0;kw<3;kw++){
      int w2 = wq+kw-1; if ((unsigned)w2 >= 128u) continue;
      acc += bf2f(A3[((size_t)((b<<14)+(h2<<7)+w2))*512 + c]) * dw[(kh*3+kw)*256 + c];
    }
  }
  outp[(size_t)r*256 + c] = f2bf(acc);
}

// ---------------- depthwise conv 2 + BN + SiLU - z_det
__global__ __launch_bounds__(256) void k_dw2(const unsigned short* __restrict__ tin,
                                             const float* __restrict__ dw,
                                             const float* __restrict__ bg,
                                             const float* __restrict__ bm_,
                                             const float* __restrict__ bv,
                                             const unsigned short* __restrict__ zdet,
                                             unsigned short* __restrict__ zcx){
  int r = blockIdx.x, c = threadIdx.x;
  int wq = r & 127, h = (r>>7)&127, b = r>>14;
  float acc = 0.f;
  #pragma unroll
  for (int kh=0;kh<3;kh++){
    int h2 = h+kh-1; if ((unsigned)h2 >= 128u) continue;
    #pragma unroll
    for (int kw=0;kw<3;kw++){
      int w2 = wq+kw-1; if ((unsigned)w2 >= 128u) continue;
      acc += bf2f(tin[((size_t)((b<<14)+(h2<<7)+w2))*256 + c]) * dw[(kh*3+kw)*256 + c];
    }
  }
  float t = (acc - bm_[c]) * rsqrtf(bv[c] + 1e-3f) * bg[c];
  t = t / (1.f + __expf(-t));
  float z = t - bf2f(zdet[(size_t)r*256 + c]);
  zcx[(size_t)r*256 + c] = f2bf(z);
}

// ---------------- generic MFMA GEMM: C = A[M,K] * (Bt[N,K])^T, 128x128 tile, BK=64
// XOR-swizzled LDS (rule #21: linear gll dest + pre-swizzled SOURCE + swizzled read)
template<int EPI>
__global__ __launch_bounds__(256) void k_gemm(const unsigned short* __restrict__ A, int lda,
                                              const unsigned short* __restrict__ Bt, int K,
                                              unsigned short* __restrict__ outbf,
                                              const float* __restrict__ xin,
                                              const unsigned short* __restrict__ A3,
                                              const float* __restrict__ gls,
                                              float* __restrict__ out){
  __shared__ unsigned short As[128*64];
  __shared__ unsigned short Bs[128*64];
  const int tid=threadIdx.x, lane=tid&63, wid=tid>>6;
  const int bm = blockIdx.x*128, bn = blockIdx.y*128;
  const int wr = wid>>1, wc = wid&1;
  f32x4 acc[4][4] = {};
  const int nk = K>>6;
  // staging: lane covers row = q*8 + (lane>>3); source k pre-swizzled
  const int srow = lane>>3;
  const int skc  = ((lane&7) ^ srow) * 8;
  for (int t=0; t<nk; ++t){
    int k0 = t*64;
    #pragma unroll
    for (int i=0;i<4;i++){
      int q = wid*4 + i;
      int row = q*8 + srow;
      gll16(A  + (size_t)(bm+row)*lda + k0 + skc, &As[q*512]);
      gll16(Bt + (size_t)(bn+row)*K   + k0 + skc, &Bs[q*512]);
    }
    __syncthreads();
    #pragma unroll
    for (int kk=0; kk<2; ++kk){
      bf16x8 af[4], bfr[4];
      #pragma unroll
      for (int i=0;i<4;i++){
        int rl = wr*64 + i*16 + (lane&15);
        int kc = (kk*32 + (lane>>4)*8) ^ ((rl&7)*8);
        af[i]  = *(const bf16x8*)&As[rl*64 + kc];
        int cl = wc*64 + i*16 + (lane&15);
        int kcb = (kk*32 + (lane>>4)*8) ^ ((cl&7)*8);
        bfr[i] = *(const bf16x8*)&Bs[cl*64 + kcb];
      }
      #pragma unroll
      for (int i=0;i<4;i++)
        #pragma unroll
        for (int j=0;j<4;j++)
          acc[i][j] = __builtin_amdgcn_mfma_f32_16x16x32_bf16(af[i], bfr[j], acc[i][j], 0,0,0);
    }
    __syncthreads();
  }
  #pragma unroll
  for (int i=0;i<4;i++)
    #pragma unroll
    for (int j=0;j<4;j++)
      #pragma unroll
      for (int r=0;r<4;r++){
        int row = bm + wr*64 + i*16 + (lane>>4)*4 + r;
        int col = bn + wc*64 + j*16 + (lane&15);
        float v = acc[i][j][r];
        if constexpr (EPI==0){
          outbf[(size_t)row*256 + col] = f2bf(v);
        } else {
          float alpha = 1.f/(1.f+__expf(-v));
          float xnv = bf2f(A3[(size_t)row*512 + col]);
          float gfv = bf2f(A3[(size_t)row*512 + 256 + col]);
          float sl = xnv/(1.f+__expf(-xnv));
          out[(size_t)row*256 + col] = xin[(size_t)row*256 + col] + (sl + alpha*gfv)*gls[col];
        }
      }
}

// ---------------- fused geo GEMM, reformulated: K=2816 (11 segs x 256)
// A-features: segs0-7 zd*roll(zc,t), t in {+1,-1,+2,-2,+4,-4,+8,-8};
// segs8-9 zd*roll(zd,s), s in {1,2}; seg10 zd (weight = per-image W_eff).
template<int S>
__device__ __attribute__((always_inline)) ushort8 shsel(ushort8 hi, ushort8 lo){
  ushort8 r;
  if constexpr (S==0) return hi;
  #pragma unroll
  for (int e=0;e<8;e++) r[e] = (e<S) ? lo[8-S+e] : hi[e-S];
  return r;
}

__device__ __attribute__((always_inline)) bf16x8 prod_bf(const float* fz, ushort8 sel){
  uint4v s = __builtin_bit_cast(uint4v, sel);
  unsigned o0,o1,o2,o3;
  float a,b;
  a = fz[0]*__builtin_bit_cast(float, s[0]<<16);
  b = fz[1]*__builtin_bit_cast(float, s[0]&0xffff0000u);
  asm("v_cvt_pk_bf16_f32 %0, %1, %2" : "=v"(o0) : "v"(a), "v"(b));
  a = fz[2]*__builtin_bit_cast(float, s[1]<<16);
  b = fz[3]*__builtin_bit_cast(float, s[1]&0xffff0000u);
  asm("v_cvt_pk_bf16_f32 %0, %1, %2" : "=v"(o1) : "v"(a), "v"(b));
  a = fz[4]*__builtin_bit_cast(float, s[2]<<16);
  b = fz[5]*__builtin_bit_cast(float, s[2]&0xffff0000u);
  asm("v_cvt_pk_bf16_f32 %0, %1, %2" : "=v"(o2) : "v"(a), "v"(b));
  a = fz[6]*__builtin_bit_cast(float, s[3]<<16);
  b = fz[7]*__builtin_bit_cast(float, s[3]&0xffff0000u);
  asm("v_cvt_pk_bf16_f32 %0, %1, %2" : "=v"(o3) : "v"(a), "v"(b));
  uint4v r = {o0,o1,o2,o3};
  return __builtin_bit_cast(bf16x8, r);
}

template<int SEG>
__device__ __attribute__((always_inline)) bf16x8 gen2(const float* fzd,
      ushort8 zch, ushort8 zcl, ushort8 zcu, ushort8 zdh, ushort8 zdl){
  if constexpr (SEG==10) return __builtin_bit_cast(bf16x8, zdh);
  ushort8 sel;
  if constexpr      (SEG==0) sel = shsel<1>(zch, zcl);
  else if constexpr (SEG==1) sel = shsel<7>(zcu, zch);
  else if constexpr (SEG==2) sel = shsel<2>(zch, zcl);
  else if constexpr (SEG==3) sel = shsel<6>(zcu, zch);
  else if constexpr (SEG==4) sel = shsel<4>(zch, zcl);
  else if constexpr (SEG==5) sel = shsel<4>(zcu, zch);
  else if constexpr (SEG==6) sel = __builtin_bit_cast(ushort8, zcl);
  else if constexpr (SEG==7) sel = __builtin_bit_cast(ushort8, zcu);
  else if constexpr (SEG==8) sel = shsel<1>(zdh, zdl);
  else                       sel = shsel<2>(zdh, zdl);
  return prod_bf(fzd, sel);
}

__global__ __launch_bounds__(256) void k_geo(const unsigned short* __restrict__ zd,
                                             const unsigned short* __restrict__ zc,
                                             const unsigned short* __restrict__ WT_all,
                                             const unsigned short* __restrict__ WeffT,
                                             unsigned short* __restrict__ A3){
  __shared__ unsigned short Bs[2][8192];     // [256 n][32 k] per buffer, XOR-swizzled slots
  const int tid = threadIdx.x, lane = tid&63, wid = tid>>6;
  const int bm = blockIdx.x*64;
  const int img = blockIdx.x >> 8;           // 256 row-blocks per image
  const int wr = wid>>1, wc = wid&1;         // wave: 32 rows x 128 cols
  f32x4 acc0[8] = {}, acc1[8] = {};

  // staging map: thread covers 4 chunks; LDS linear dest, source k-slot pre-swizzled
  const int s4 = tid & 3;
  int inv0, inv1, inv2, inv3;
  {
    int n; int sw;
    n = 0*64 + (tid>>2); sw = (n + (n>>2)) & 3; inv0 = n*256 + ((s4^sw)<<3);
    n = 1*64 + (tid>>2); sw = (n + (n>>2)) & 3; inv1 = n*256 + ((s4^sw)<<3);
    n = 2*64 + (tid>>2); sw = (n + (n>>2)) & 3; inv2 = n*256 + ((s4^sw)<<3);
    n = 3*64 + (tid>>2); sw = (n + (n>>2)) & 3; inv3 = n*256 + ((s4^sw)<<3);
  }
  // read offsets (elems) for the 8 B fragments, swizzle-matched
  int roff[8];
  #pragma unroll
  for (int fj=0; fj<8; ++fj){
    int n = wc*128 + fj*16 + (lane&15);
    int sw = (n + (n>>2)) & 3;
    roff[fj] = n*32 + ((((lane>>4)) ^ sw) << 3);
  }

  const int m0 = bm + wr*32 + (lane&15);
  const int m1 = m0 + 16;
  const unsigned short* zdr0 = zd + (size_t)m0*256;
  const unsigned short* zdr1 = zd + (size_t)m1*256;
  const unsigned short* zcr0 = zc + (size_t)m0*256;
  const unsigned short* zcr1 = zc + (size_t)m1*256;

  ushort8 zch0,zcl0,zcu0,zdh0,zdl0, zch1,zcl1,zcu1,zdh1,zdl1;
  float fzd0[8], fzd1[8];
  int cur = 0;

#define STAGE(BUF, SP, KK) { \
    const unsigned short* Wb = ((SP)<10) ? (WT_all + (SP)*65536) : (WeffT + (size_t)img*65536); \
    const unsigned short* Wk = Wb + (KK)*32; \
    gll16(Wk + inv0, &Bs[BUF][0*2048 + wid*512]); \
    gll16(Wk + inv1, &Bs[BUF][1*2048 + wid*512]); \
    gll16(Wk + inv2, &Bs[BUF][2*2048 + wid*512]); \
    gll16(Wk + inv3, &Bs[BUF][3*2048 + wid*512]); \
  }

  STAGE(0, 0, 0);
  __syncthreads();

#define SEGSTEP(S, SP, KINC) { \
    if ((KINC)==0 || k32<7) STAGE(cur^1, SP, k32+(KINC)); \
    bf16x8 af0 = gen2<S>(fzd0, zch0, zcl0, zcu0, zdh0, zdl0); \
    bf16x8 af1 = gen2<S>(fzd1, zch1, zcl1, zcu1, zdh1, zdl1); \
    const unsigned short* bp = &Bs[cur][0]; \
    _Pragma("unroll") \
    for (int fj=0; fj<8; ++fj){ \
      bf16x8 bfr = *(const bf16x8*)&bp[roff[fj]]; \
      acc0[fj] = __builtin_amdgcn_mfma_f32_16x16x32_bf16(af0, bfr, acc0[fj], 0,0,0); \
      acc1[fj] = __builtin_amdgcn_mfma_f32_16x16x32_bf16(af1, bfr, acc1[fj], 0,0,0); \
    } \
    __syncthreads(); \
    cur ^= 1; \
  }

  for (int k32=0; k32<8; ++k32){
    int kc = k32*32 + (lane>>4)*8;
    int kl = (kc-8)&255, ku = (kc+8)&255;
    zdh0 = *(const ushort8*)(zdr0 + kc); zdl0 = *(const ushort8*)(zdr0 + kl);
    zch0 = *(const ushort8*)(zcr0 + kc); zcl0 = *(const ushort8*)(zcr0 + kl);
    zcu0 = *(const ushort8*)(zcr0 + ku);
    zdh1 = *(const ushort8*)(zdr1 + kc); zdl1 = *(const ushort8*)(zdr1 + kl);
    zch1 = *(const ushort8*)(zcr1 + kc); zcl1 = *(const ushort8*)(zcr1 + kl);
    zcu1 = *(const ushort8*)(zcr1 + ku);
    {
      uint4v d0 = __builtin_bit_cast(uint4v, zdh0);
      uint4v d1 = __builtin_bit_cast(uint4v, zdh1);
      #pragma unroll
      for (int p=0;p<4;p++){
        fzd0[2*p]   = __builtin_bit_cast(float, d0[p]<<16);
        fzd0[2*p+1] = __builtin_bit_cast(float, d0[p]&0xffff0000u);
        fzd1[2*p]   = __builtin_bit_cast(float, d1[p]<<16);
        fzd1[2*p+1] = __builtin_bit_cast(float, d1[p]&0xffff0000u);
      }
    }
    SEGSTEP(0,1,0)  SEGSTEP(1,2,0)  SEGSTEP(2,3,0)  SEGSTEP(3,4,0)
    SEGSTEP(4,5,0)  SEGSTEP(5,6,0)  SEGSTEP(6,7,0)  SEGSTEP(7,8,0)
    SEGSTEP(8,9,0)  SEGSTEP(9,10,0) SEGSTEP(10,0,1)
  }
#undef SEGSTEP
#undef STAGE

  #pragma unroll
  for (int fj=0; fj<8; ++fj)
    #pragma unroll
    for (int r=0; r<4; ++r){
      int col = wc*128 + fj*16 + (lane&15);
      int row0 = bm + wr*32 + (lane>>4)*4 + r;
      A3[(size_t)row0*512 + 256 + col] = f2bf(acc0[fj][r]);
      A3[(size_t)(row0+16)*512 + 256 + col] = f2bf(acc1[fj][r]);
    }
}

extern "C" void kernel_launch(void* const* d_in, const int* in_sizes, int n_in,
                              void* d_out, int out_size, void* d_ws, size_t ws_size,
                              hipStream_t stream){
  (void)in_sizes; (void)n_in; (void)out_size; (void)ws_size;
  const float* x    = (const float*)d_in[0];
  const float* lng  = (const float*)d_in[1];
  const float* wdet = (const float*)d_in[2];
  const float* dw1  = (const float*)d_in[3];
  const float* dw2  = (const float*)d_in[4];
  const float* bng  = (const float*)d_in[5];
  const float* bnm  = (const float*)d_in[6];
  const float* bnv  = (const float*)d_in[7];
  const float* wloc = (const float*)d_in[8];
  const float* wglo = (const float*)d_in[9];
  const float* wgat = (const float*)d_in[10];
  const float* gls  = (const float*)d_in[11];
  float* out = (float*)d_out;
  char* ws = (char*)d_ws;

  unsigned short* A3     = (unsigned short*)(ws);                 // 64 MB [65536][512]
  unsigned short* ZDET   = (unsigned short*)(ws + 67108864);      // 32 MB
  unsigned short* TMP    = (unsigned short*)(ws + 100663296);     // 32 MB
  unsigned short* ZCX    = (unsigned short*)(ws + 134217728);     // 32 MB
  unsigned short* WTALL  = (unsigned short*)(ws + 167772160);     // 1.25 MB [10][256][256]
  unsigned short* WEFFT  = (unsigned short*)(ws + 169213952);     // 0.5 MB [4][256][256]
  unsigned short* WDETT  = (unsigned short*)(ws + 169738240);     // 128 KB
  unsigned short* WGATET = (unsigned short*)(ws + 169869312);     // 256 KB
  float* PSUM  = (float*)(ws + 170131456);                        // 256 KB
  float* MMEAN = (float*)(ws + 170393600);                        // 4 KB

  k_ln<<<65536, 256, 0, stream>>>(x, lng, A3);
  k_cm1<<<256, 256, 0, stream>>>(A3, PSUM);
  k_cm2<<<4, 256, 0, stream>>>(PSUM, MMEAN);
  k_prep_nt<<<256, 256, 0, stream>>>(wdet, WDETT, 256);
  k_prep_nt<<<512, 256, 0, stream>>>(wgat, WGATET, 512);
  k_prep_geoT<<<2560, 256, 0, stream>>>(wloc, wglo, WTALL);
  k_prep_weff<<<1024, 256, 0, stream>>>(wglo, MMEAN, WEFFT);
  k_gemm<0><<<dim3(512,2), 256, 0, stream>>>(A3, 512, WDETT, 256, ZDET,
                                             nullptr, nullptr, nullptr, nullptr);
  k_dw1<<<65536, 256, 0, stream>>>(A3, dw1, TMP);
  k_dw2<<<65536, 256, 0, stream>>>(TMP, dw2, bng, bnm, bnv, ZDET, ZCX);
  k_geo<<<1024, 256, 0, stream>>>(ZDET, ZCX, WTALL, WEFFT, A3);
  k_gemm<1><<<dim3(512,2), 256, 0, stream>>>(A3, 512, WGATET, 512, nullptr,
                                             x, A3, gls, out);
}

// Round 3
// 356.444 us; speedup vs baseline: 1.9426x; 1.4447x over previous
//
#include <hip/hip_runtime.h>

typedef __attribute__((ext_vector_type(8))) short bf16x8;
typedef __attribute__((ext_vector_type(8))) unsigned short ushort8;
typedef __attribute__((ext_vector_type(4))) unsigned short ushort4v;
typedef __attribute__((ext_vector_type(4))) float f32x4;
typedef __attribute__((ext_vector_type(8))) _Float16 f16x8;

__device__ inline unsigned short f2bf(float f){
  unsigned u = __builtin_bit_cast(unsigned, f);
  return (unsigned short)((u + 0x7fffu + ((u>>16)&1u)) >> 16);
}
__device__ inline float bf2f(unsigned short h){
  return __builtin_bit_cast(float, (unsigned)h << 16);
}
__device__ inline unsigned short f2h(float f){
  return __builtin_bit_cast(unsigned short, (_Float16)f);
}
__device__ inline float h2f(unsigned short u){
  return (float)__builtin_bit_cast(_Float16, u);
}

__device__ inline void gll16(const void* g, void* l){
  __builtin_amdgcn_global_load_lds((const __attribute__((address_space(1))) void*)g,
                                   (__attribute__((address_space(3))) void*)l, 16, 0, 0);
}

// ---------------- LayerNorm: x (f32) -> x_norm bf16 into A3[:, 0:256] (row stride 512)
__global__ __launch_bounds__(256) void k_ln(const float* __restrict__ x,
                                            const float* __restrict__ g,
                                            unsigned short* __restrict__ A3){
  int r = blockIdx.x, c = threadIdx.x;
  float v = x[(size_t)r*256 + c];
  float s = v, s2 = v*v;
  #pragma unroll
  for (int m=32; m>=1; m>>=1){ s += __shfl_xor(s, m, 64); s2 += __shfl_xor(s2, m, 64); }
  __shared__ float rs[4], rs2[4];
  int wid = c>>6, lane = c&63;
  if (lane==0){ rs[wid]=s; rs2[wid]=s2; }
  __syncthreads();
  float ts  = rs[0]+rs[1]+rs[2]+rs[3];
  float ts2 = rs2[0]+rs2[1]+rs2[2]+rs2[3];
  float mu  = ts*(1.f/256.f);
  float var = ts2*(1.f/256.f) - mu*mu;
  float xn = (v-mu)*rsqrtf(var + 1e-6f)*g[c];
  A3[(size_t)r*512 + c] = f2bf(xn);
}

// ---------------- column means of x_norm per image
__global__ __launch_bounds__(256) void k_cm1(const unsigned short* __restrict__ A3,
                                             float* __restrict__ psum){
  int blk = blockIdx.x;
  int c = threadIdx.x;
  const unsigned short* base = A3 + (size_t)blk*256*512;
  float s = 0.f;
  for (int p=0;p<256;p++) s += bf2f(base[(size_t)p*512 + c]);
  psum[blk*256 + c] = s;
}
__global__ __launch_bounds__(256) void k_cm2(const float* __restrict__ psum,
                                             float* __restrict__ m){
  int b = blockIdx.x, c = threadIdx.x;
  float s = 0.f;
  for (int ch=0; ch<64; ch++) s += psum[(b*64+ch)*256 + c];
  m[b*256 + c] = s*(1.f/16384.f);
}

// ---------------- weight transposes to bf16 (Bt layout [N][K]) for the two GEMMs
__global__ __launch_bounds__(256) void k_prep_nt(const float* __restrict__ W,
                                                 unsigned short* __restrict__ WT, int K){
  int idx = blockIdx.x*256 + threadIdx.x;
  int j = idx / K, k = idx - j*K;
  WT[idx] = f2bf(W[(size_t)k*256 + j]);
}

// geo weights -> FP16. WT_all: [10][256 n][256 k]:
// seg 2i   (t=+s): Wi_s + Ww_s               (feature zd[c]*zc[c-s])
// seg 2i+1 (t=-s): (Wi_s - Ww_s)[(k+s)%C,:]  (feature zd[c]*zc[c+s])
// seg 8+j: -2*Wi_global[j]                   (feature zd[c]*zd[c-s_j])
__global__ __launch_bounds__(256) void k_prep_geoT(const float* __restrict__ wl,
                                                   const float* __restrict__ wg,
                                                   unsigned short* __restrict__ WT){
  int idx = blockIdx.x*256 + threadIdx.x;
  int sg = idx >> 16, rem = idx & 65535;
  int j = rem >> 8, k = rem & 255;
  float v;
  if (sg < 8){
    int si = sg >> 1, s = 1 << si;
    bool neg = sg & 1;
    int krow = neg ? ((k + s) & 255) : k;
    float wi = wl[(size_t)((2*si)*256 + krow)*256 + j];
    float ww = wl[(size_t)((2*si+1)*256 + krow)*256 + j];
    v = neg ? (wi - ww) : (wi + ww);
  } else {
    v = -2.f * wg[(size_t)((sg-8)*2*256 + k)*256 + j];
  }
  WT[idx] = f2h(v);
}

// W_eff (fp16, transposed [b][j][c])
__global__ __launch_bounds__(256) void k_prep_weff(const float* __restrict__ wg,
                                                   const float* __restrict__ m,
                                                   unsigned short* __restrict__ WT){
  int b = blockIdx.x >> 8, c = blockIdx.x & 255, j = threadIdx.x;
  float acc = 0.f;
  #pragma unroll
  for (int si=0; si<2; ++si){
    int s = si+1;
    int cm = (c - s) & 255, cp = (c + s) & 255;
    float wi_c  = wg[(size_t)((2*si)*256 + c)*256 + j];
    float ww_c  = wg[(size_t)((2*si+1)*256 + c)*256 + j];
    float wi_cp = wg[(size_t)((2*si)*256 + cp)*256 + j];
    float ww_cp = wg[(size_t)((2*si+1)*256 + cp)*256 + j];
    acc += m[b*256+cm]*(wi_c+ww_c) + m[b*256+cp]*(wi_cp-ww_cp);
  }
  WT[(size_t)b*65536 + (size_t)j*256 + c] = f2h(acc);
}

// ---------------- fused depthwise 3x3 + 3x3 + BN + SiLU - z_det
// tile 16x16 px, 32 ch per block; t0 halo-2 staged, t1 intermediate (OOB zeroed).
__global__ __launch_bounds__(256) void k_dwf(const unsigned short* __restrict__ A3,
                                             const float* __restrict__ w1g,
                                             const float* __restrict__ w2g,
                                             const float* __restrict__ bg,
                                             const float* __restrict__ bm_,
                                             const float* __restrict__ bv,
                                             const unsigned short* __restrict__ zdet,
                                             unsigned short* __restrict__ zcx){
  __shared__ unsigned short t0[12800];   // [20][20][32] bf16
  __shared__ unsigned short t1[10368];   // [18][18][32] fp16
  int t = blockIdx.x;
  int img = t >> 6, ty = (t>>3)&7, tx = t&7;
  int c0 = blockIdx.y*32;
  int tid = threadIdx.x;
  int ch = tid & 31;
  int c = c0 + ch;
  // stage t0 (ushort4 vectors): 3200 vec4s
  for (int v = tid; v < 3200; v += 256){
    int py = v / 160, rem = v - py*160;
    int px = rem >> 3, ch4 = (rem & 7)*4;
    int gpy = ty*16 - 2 + py, gpx = tx*16 - 2 + px;
    ushort4v val = {0,0,0,0};
    if ((unsigned)gpy < 128u && (unsigned)gpx < 128u){
      size_t gp = (size_t)(img*16384 + gpy*128 + gpx);
      val = *(const ushort4v*)&A3[gp*512 + c0 + ch4];
    }
    *(ushort4v*)&t0[(py*20+px)*32 + ch4] = val;
  }
  float w1[9], w2[9];
  #pragma unroll
  for (int k=0;k<9;k++){ w1[k] = w1g[k*256 + c]; w2[k] = w2g[k*256 + c]; }
  __syncthreads();
  // conv1 -> t1 (18x18), zero at OOB global positions
  for (int p = tid>>5; p < 324; p += 8){
    int py = p / 18, px = p - py*18;
    int gpy = ty*16 - 1 + py, gpx = tx*16 - 1 + px;
    float acc = 0.f;
    #pragma unroll
    for (int dy=0; dy<3; ++dy)
      #pragma unroll
      for (int dx=0; dx<3; ++dx)
        acc += bf2f(t0[((py+dy)*20 + px+dx)*32 + ch]) * w1[dy*3+dx];
    bool valid = ((unsigned)gpy < 128u) && ((unsigned)gpx < 128u);
    t1[p*32 + ch] = valid ? f2h(acc) : (unsigned short)0;
  }
  __syncthreads();
  float bmv = bm_[c];
  float rsbg = rsqrtf(bv[c] + 1e-3f) * bg[c];
  for (int p = tid>>5; p < 256; p += 8){
    int py = p >> 4, px = p & 15;
    float acc = 0.f;
    #pragma unroll
    for (int dy=0; dy<3; ++dy)
      #pragma unroll
      for (int dx=0; dx<3; ++dx)
        acc += h2f(t1[((py+dy)*18 + px+dx)*32 + ch]) * w2[dy*3+dx];
    float tv = (acc - bmv) * rsbg;
    float sv = tv / (1.f + __expf(-tv));
    size_t gp = (size_t)(img*16384 + (ty*16+py)*128 + tx*16+px);
    float z = sv - h2f(zdet[gp*256 + c]);
    zcx[gp*256 + c] = f2h(z);
  }
}

// ---------------- generic MFMA GEMM: C = A[M,K] * (Bt[N,K])^T, 128x128 tile, BK=64
template<int EPI>
__global__ __launch_bounds__(256) void k_gemm(const unsigned short* __restrict__ A, int lda,
                                              const unsigned short* __restrict__ Bt, int K,
                                              unsigned short* __restrict__ outh,
                                              const float* __restrict__ xin,
                                              const unsigned short* __restrict__ A3,
                                              const float* __restrict__ gls,
                                              float* __restrict__ out){
  __shared__ unsigned short As[128*64];
  __shared__ unsigned short Bs[128*64];
  const int tid=threadIdx.x, lane=tid&63, wid=tid>>6;
  const int bm = blockIdx.x*128, bn = blockIdx.y*128;
  const int wr = wid>>1, wc = wid&1;
  f32x4 acc[4][4] = {};
  const int nk = K>>6;
  const int srow = lane>>3;
  const int skc  = ((lane&7) ^ srow) * 8;
  for (int t=0; t<nk; ++t){
    int k0 = t*64;
    #pragma unroll
    for (int i=0;i<4;i++){
      int q = wid*4 + i;
      int row = q*8 + srow;
      gll16(A  + (size_t)(bm+row)*lda + k0 + skc, &As[q*512]);
      gll16(Bt + (size_t)(bn+row)*K   + k0 + skc, &Bs[q*512]);
    }
    __syncthreads();
    #pragma unroll
    for (int kk=0; kk<2; ++kk){
      bf16x8 af[4], bfr[4];
      #pragma unroll
      for (int i=0;i<4;i++){
        int rl = wr*64 + i*16 + (lane&15);
        int kc = (kk*32 + (lane>>4)*8) ^ ((rl&7)*8);
        af[i]  = *(const bf16x8*)&As[rl*64 + kc];
        int cl = wc*64 + i*16 + (lane&15);
        int kcb = (kk*32 + (lane>>4)*8) ^ ((cl&7)*8);
        bfr[i] = *(const bf16x8*)&Bs[cl*64 + kcb];
      }
      #pragma unroll
      for (int i=0;i<4;i++)
        #pragma unroll
        for (int j=0;j<4;j++)
          acc[i][j] = __builtin_amdgcn_mfma_f32_16x16x32_bf16(af[i], bfr[j], acc[i][j], 0,0,0);
    }
    __syncthreads();
  }
  #pragma unroll
  for (int i=0;i<4;i++)
    #pragma unroll
    for (int j=0;j<4;j++)
      #pragma unroll
      for (int r=0;r<4;r++){
        int row = bm + wr*64 + i*16 + (lane>>4)*4 + r;
        int col = bn + wc*64 + j*16 + (lane&15);
        float v = acc[i][j][r];
        if constexpr (EPI==0){
          outh[(size_t)row*256 + col] = f2h(v);   // z_det in FP16
        } else {
          float alpha = 1.f/(1.f+__expf(-v));
          float xnv = bf2f(A3[(size_t)row*512 + col]);
          float gfv = bf2f(A3[(size_t)row*512 + 256 + col]);
          float sl = xnv/(1.f+__expf(-xnv));
          out[(size_t)row*256 + col] = xin[(size_t)row*256 + col] + (sl + alpha*gfv)*gls[col];
        }
      }
}

// ---------------- fused geo GEMM, FP16 features, ring-3 counted-vmcnt pipeline
template<int S>
__device__ __attribute__((always_inline)) ushort8 shsel(ushort8 hi, ushort8 lo){
  ushort8 r;
  if constexpr (S==0) return hi;
  #pragma unroll
  for (int e=0;e<8;e++) r[e] = (e<S) ? lo[8-S+e] : hi[e-S];
  return r;
}

template<int SEG>
__device__ __attribute__((always_inline)) f16x8 gen2(ushort8 zdh, ushort8 zdl,
      ushort8 zch, ushort8 zcl, ushort8 zcu){
  if constexpr (SEG==10) return __builtin_bit_cast(f16x8, zdh);
  ushort8 sel;
  if constexpr      (SEG==0) sel = shsel<1>(zch, zcl);
  else if constexpr (SEG==1) sel = shsel<7>(zcu, zch);
  else if constexpr (SEG==2) sel = shsel<2>(zch, zcl);
  else if constexpr (SEG==3) sel = shsel<6>(zcu, zch);
  else if constexpr (SEG==4) sel = shsel<4>(zch, zcl);
  else if constexpr (SEG==5) sel = shsel<4>(zcu, zch);
  else if constexpr (SEG==6) sel = zcl;
  else if constexpr (SEG==7) sel = zcu;
  else if constexpr (SEG==8) sel = shsel<1>(zdh, zdl);
  else                       sel = shsel<2>(zdh, zdl);
  return __builtin_bit_cast(f16x8, zdh) * __builtin_bit_cast(f16x8, sel);
}

__global__ __launch_bounds__(256) void k_geo(const unsigned short* __restrict__ zd,
                                             const unsigned short* __restrict__ zc,
                                             const unsigned short* __restrict__ WT_all,
                                             const unsigned short* __restrict__ WeffT,
                                             unsigned short* __restrict__ A3){
  __shared__ unsigned short Bs[3][8192];     // [256 n][32 k] fp16, XOR-swizzled slots
  const int tid = threadIdx.x, lane = tid&63, wid = tid>>6;
  const int bm = blockIdx.x*64;
  const int img = blockIdx.x >> 8;
  const int wr = wid>>1, wc = wid&1;         // wave: 32 rows x 128 cols
  f32x4 acc0[8] = {}, acc1[8] = {};

  const int s4 = tid & 3;
  int inv[4];
  #pragma unroll
  for (int g=0; g<4; ++g){
    int n = g*64 + (tid>>2);
    int sw = (n + (n>>2)) & 3;
    inv[g] = n*256 + ((s4^sw)<<3);
  }
  int roff[8];
  #pragma unroll
  for (int fj=0; fj<8; ++fj){
    int n = wc*128 + fj*16 + (lane&15);
    int sw = (n + (n>>2)) & 3;
    roff[fj] = n*32 + (((lane>>4) ^ sw) << 3);
  }

  const int m0 = bm + wr*32 + (lane&15);
  const unsigned short* zdr0 = zd + (size_t)m0*256;
  const unsigned short* zdr1 = zdr0 + 16*256;
  const unsigned short* zcr0 = zc + (size_t)m0*256;
  const unsigned short* zcr1 = zcr0 + 16*256;

  ushort8 zdh0,zdl0,zch0,zcl0,zcu0, zdh1,zdl1,zch1,zcl1,zcu1;
  int cur = 0;

#define STAGE(BUF, SP, KK) { \
    const unsigned short* Wb = ((SP)<10) ? (WT_all + (SP)*65536) : (WeffT + (size_t)img*65536); \
    const unsigned short* Wk = Wb + (KK)*32; \
    gll16(Wk + inv[0], &Bs[BUF][0*2048 + wid*512]); \
    gll16(Wk + inv[1], &Bs[BUF][1*2048 + wid*512]); \
    gll16(Wk + inv[2], &Bs[BUF][2*2048 + wid*512]); \
    gll16(Wk + inv[3], &Bs[BUF][3*2048 + wid*512]); \
  }

  STAGE(0, 0, 0);
  STAGE(1, 1, 0);

#define STEP(P) { \
    asm volatile("s_waitcnt vmcnt(4)" ::: "memory"); \
    __builtin_amdgcn_s_barrier(); \
    if constexpr ((P)==0){ \
      int kc = k32*32 + (lane>>4)*8; \
      int kl = (kc-8)&255, ku = (kc+8)&255; \
      zdh0 = *(const ushort8*)(zdr0 + kc); zdl0 = *(const ushort8*)(zdr0 + kl); \
      zch0 = *(const ushort8*)(zcr0 + kc); zcl0 = *(const ushort8*)(zcr0 + kl); \
      zcu0 = *(const ushort8*)(zcr0 + ku); \
      zdh1 = *(const ushort8*)(zdr1 + kc); zdl1 = *(const ushort8*)(zdr1 + kl); \
      zch1 = *(const ushort8*)(zcr1 + kc); zcl1 = *(const ushort8*)(zcr1 + kl); \
      zcu1 = *(const ushort8*)(zcr1 + ku); \
    } \
    __builtin_amdgcn_sched_barrier(0); \
    { constexpr int s2 = ((P)+2 <= 10) ? (P)+2 : (P)+2-11; \
      int k2 = k32 + (((P)+2 > 10) ? 1 : 0); if (k2 > 7) k2 = 7; \
      int nbuf = cur+2; if (nbuf >= 3) nbuf -= 3; \
      STAGE(nbuf, s2, k2); } \
    __builtin_amdgcn_sched_barrier(0); \
    f16x8 af0 = gen2<(P)>(zdh0,zdl0,zch0,zcl0,zcu0); \
    f16x8 af1 = gen2<(P)>(zdh1,zdl1,zch1,zcl1,zcu1); \
    const unsigned short* bp = &Bs[cur][0]; \
    __builtin_amdgcn_s_setprio(1); \
    _Pragma("unroll") \
    for (int fj=0; fj<8; ++fj){ \
      f16x8 bfr = *(const f16x8*)&bp[roff[fj]]; \
      acc0[fj] = __builtin_amdgcn_mfma_f32_16x16x32_f16(af0, bfr, acc0[fj], 0,0,0); \
      acc1[fj] = __builtin_amdgcn_mfma_f32_16x16x32_f16(af1, bfr, acc1[fj], 0,0,0); \
    } \
    __builtin_amdgcn_s_setprio(0); \
    cur = cur+1; if (cur >= 3) cur -= 3; \
  }

  for (int k32=0; k32<8; ++k32){
    STEP(0) STEP(1) STEP(2) STEP(3) STEP(4) STEP(5)
    STEP(6) STEP(7) STEP(8) STEP(9) STEP(10)
  }
#undef STEP
#undef STAGE

  #pragma unroll
  for (int fj=0; fj<8; ++fj)
    #pragma unroll
    for (int r=0; r<4; ++r){
      int col = wc*128 + fj*16 + (lane&15);
      int row0 = bm + wr*32 + (lane>>4)*4 + r;
      A3[(size_t)row0*512 + 256 + col] = f2bf(acc0[fj][r]);
      A3[(size_t)(row0+16)*512 + 256 + col] = f2bf(acc1[fj][r]);
    }
}

extern "C" void kernel_launch(void* const* d_in, const int* in_sizes, int n_in,
                              void* d_out, int out_size, void* d_ws, size_t ws_size,
                              hipStream_t stream){
  (void)in_sizes; (void)n_in; (void)out_size; (void)ws_size;
  const float* x    = (const float*)d_in[0];
  const float* lng  = (const float*)d_in[1];
  const float* wdet = (const float*)d_in[2];
  const float* dw1  = (const float*)d_in[3];
  const float* dw2  = (const float*)d_in[4];
  const float* bng  = (const float*)d_in[5];
  const float* bnm  = (const float*)d_in[6];
  const float* bnv  = (const float*)d_in[7];
  const float* wloc = (const float*)d_in[8];
  const float* wglo = (const float*)d_in[9];
  const float* wgat = (const float*)d_in[10];
  const float* gls  = (const float*)d_in[11];
  float* out = (float*)d_out;
  char* ws = (char*)d_ws;

  unsigned short* A3     = (unsigned short*)(ws);                 // 64 MB [65536][512] bf16
  unsigned short* ZDET   = (unsigned short*)(ws + 67108864);      // 32 MB fp16
  unsigned short* ZCX    = (unsigned short*)(ws + 134217728);     // 32 MB fp16
  unsigned short* WTALL  = (unsigned short*)(ws + 167772160);     // 1.25 MB fp16
  unsigned short* WEFFT  = (unsigned short*)(ws + 169213952);     // 0.5 MB fp16
  unsigned short* WDETT  = (unsigned short*)(ws + 169738240);     // 128 KB bf16
  unsigned short* WGATET = (unsigned short*)(ws + 169869312);     // 256 KB bf16
  float* PSUM  = (float*)(ws + 170131456);                        // 256 KB
  float* MMEAN = (float*)(ws + 170393600);                        // 4 KB

  k_ln<<<65536, 256, 0, stream>>>(x, lng, A3);
  k_cm1<<<256, 256, 0, stream>>>(A3, PSUM);
  k_cm2<<<4, 256, 0, stream>>>(PSUM, MMEAN);
  k_prep_nt<<<256, 256, 0, stream>>>(wdet, WDETT, 256);
  k_prep_nt<<<512, 256, 0, stream>>>(wgat, WGATET, 512);
  k_prep_geoT<<<2560, 256, 0, stream>>>(wloc, wglo, WTALL);
  k_prep_weff<<<1024, 256, 0, stream>>>(wglo, MMEAN, WEFFT);
  k_gemm<0><<<dim3(512,2), 256, 0, stream>>>(A3, 512, WDETT, 256, ZDET,
                                             nullptr, nullptr, nullptr, nullptr);
  k_dwf<<<dim3(256,8), 256, 0, stream>>>(A3, dw1, dw2, bng, bnm, bnv, ZDET, ZCX);
  k_geo<<<1024, 256, 0, stream>>>(ZDET, ZCX, WTALL, WEFFT, A3);
  k_gemm<1><<<dim3(512,2), 256, 0, stream>>>(A3, 512, WGATET, 512, nullptr,
                                             x, A3, gls, out);
}

// Round 4
// 354.644 us; speedup vs baseline: 1.9525x; 1.0051x over previous
//
#include <hip/hip_runtime.h>

typedef __attribute__((ext_vector_type(8))) short bf16x8;
typedef __attribute__((ext_vector_type(8))) unsigned short ushort8;
typedef __attribute__((ext_vector_type(4))) unsigned short ushort4v;
typedef __attribute__((ext_vector_type(4))) float f32x4;
typedef __attribute__((ext_vector_type(8))) _Float16 f16x8;

__device__ inline unsigned short f2bf(float f){
  unsigned u = __builtin_bit_cast(unsigned, f);
  return (unsigned short)((u + 0x7fffu + ((u>>16)&1u)) >> 16);
}
__device__ inline float bf2f(unsigned short h){
  return __builtin_bit_cast(float, (unsigned)h << 16);
}
__device__ inline unsigned short f2h(float f){
  return __builtin_bit_cast(unsigned short, (_Float16)f);
}
__device__ inline float h2f(unsigned short u){
  return (float)__builtin_bit_cast(_Float16, u);
}

__device__ inline void gll16(const void* g, void* l){
  __builtin_amdgcn_global_load_lds((const __attribute__((address_space(1))) void*)g,
                                   (__attribute__((address_space(3))) void*)l, 16, 0, 0);
}

// ---------------- LayerNorm: x (f32) -> x_norm bf16 into A3[:, 0:256] (row stride 512)
__global__ __launch_bounds__(256) void k_ln(const float* __restrict__ x,
                                            const float* __restrict__ g,
                                            unsigned short* __restrict__ A3){
  int r = blockIdx.x, c = threadIdx.x;
  float v = x[(size_t)r*256 + c];
  float s = v, s2 = v*v;
  #pragma unroll
  for (int m=32; m>=1; m>>=1){ s += __shfl_xor(s, m, 64); s2 += __shfl_xor(s2, m, 64); }
  __shared__ float rs[4], rs2[4];
  int wid = c>>6, lane = c&63;
  if (lane==0){ rs[wid]=s; rs2[wid]=s2; }
  __syncthreads();
  float ts  = rs[0]+rs[1]+rs[2]+rs[3];
  float ts2 = rs2[0]+rs2[1]+rs2[2]+rs2[3];
  float mu  = ts*(1.f/256.f);
  float var = ts2*(1.f/256.f) - mu*mu;
  float xn = (v-mu)*rsqrtf(var + 1e-6f)*g[c];
  A3[(size_t)r*512 + c] = f2bf(xn);
}

// ---------------- column means of x_norm per image
__global__ __launch_bounds__(256) void k_cm1(const unsigned short* __restrict__ A3,
                                             float* __restrict__ psum){
  int blk = blockIdx.x;
  int c = threadIdx.x;
  const unsigned short* base = A3 + (size_t)blk*256*512;
  float s = 0.f;
  for (int p=0;p<256;p++) s += bf2f(base[(size_t)p*512 + c]);
  psum[blk*256 + c] = s;
}
__global__ __launch_bounds__(256) void k_cm2(const float* __restrict__ psum,
                                             float* __restrict__ m){
  int b = blockIdx.x, c = threadIdx.x;
  float s = 0.f;
  for (int ch=0; ch<64; ch++) s += psum[(b*64+ch)*256 + c];
  m[b*256 + c] = s*(1.f/16384.f);
}

// ---------------- weight transposes to bf16 (Bt layout [N][K]) for the two GEMMs
__global__ __launch_bounds__(256) void k_prep_nt(const float* __restrict__ W,
                                                 unsigned short* __restrict__ WT, int K){
  int idx = blockIdx.x*256 + threadIdx.x;
  int j = idx / K, k = idx - j*K;
  WT[idx] = f2bf(W[(size_t)k*256 + j]);
}

// geo weights -> FP16 in LDS-ready layout [10][8 k32][4 q][256 n][8 e]:
// element (sg, k = k32*32+q*8+e, n=j):
// seg 2i   (t=+s): Wi_s + Ww_s               (feature zd[c]*zc[c-s])
// seg 2i+1 (t=-s): (Wi_s - Ww_s)[(k+s)%C,:]  (feature zd[c]*zc[c+s])
// seg 8+j: -2*Wi_global[j]                   (feature zd[c]*zd[c-s_j])
__global__ __launch_bounds__(256) void k_prep_geoT(const float* __restrict__ wl,
                                                   const float* __restrict__ wg,
                                                   unsigned short* __restrict__ WT){
  int idx = blockIdx.x*256 + threadIdx.x;     // over 10*65536, output-linear
  int e = idx & 7, n = (idx>>3)&255, q = (idx>>11)&3, k32 = (idx>>13)&7, sg = idx>>16;
  int k = k32*32 + q*8 + e;
  int j = n;
  float v;
  if (sg < 8){
    int si = sg >> 1, s = 1 << si;
    bool neg = sg & 1;
    int krow = neg ? ((k + s) & 255) : k;
    float wi = wl[(size_t)((2*si)*256 + krow)*256 + j];
    float ww = wl[(size_t)((2*si+1)*256 + krow)*256 + j];
    v = neg ? (wi - ww) : (wi + ww);
  } else {
    v = -2.f * wg[(size_t)((sg-8)*2*256 + k)*256 + j];
  }
  WT[idx] = f2h(v);
}

// W_eff (fp16) in layout [b][8 k32][4 q][256 n=j][8 e], where k(c) = k32*32+q*8+e
__global__ __launch_bounds__(256) void k_prep_weff(const float* __restrict__ wg,
                                                   const float* __restrict__ m,
                                                   unsigned short* __restrict__ WT){
  int b = blockIdx.x >> 8, c = blockIdx.x & 255, j = threadIdx.x;
  float acc = 0.f;
  #pragma unroll
  for (int si=0; si<2; ++si){
    int s = si+1;
    int cm = (c - s) & 255, cp = (c + s) & 255;
    float wi_c  = wg[(size_t)((2*si)*256 + c)*256 + j];
    float ww_c  = wg[(size_t)((2*si+1)*256 + c)*256 + j];
    float wi_cp = wg[(size_t)((2*si)*256 + cp)*256 + j];
    float ww_cp = wg[(size_t)((2*si+1)*256 + cp)*256 + j];
    acc += m[b*256+cm]*(wi_c+ww_c) + m[b*256+cp]*(wi_cp-ww_cp);
  }
  size_t addr = (size_t)b*65536 + (size_t)(c>>5)*8192 + (size_t)((c>>3)&3)*2048
              + (size_t)j*8 + (c&7);
  WT[addr] = f2h(acc);
}

// ---------------- fused depthwise 3x3 + 3x3 + BN + SiLU - z_det
__global__ __launch_bounds__(256) void k_dwf(const unsigned short* __restrict__ A3,
                                             const float* __restrict__ w1g,
                                             const float* __restrict__ w2g,
                                             const float* __restrict__ bg,
                                             const float* __restrict__ bm_,
                                             const float* __restrict__ bv,
                                             const unsigned short* __restrict__ zdet,
                                             unsigned short* __restrict__ zcx){
  __shared__ unsigned short t0[12800];   // [20][20][32] bf16
  __shared__ unsigned short t1[10368];   // [18][18][32] fp16
  int t = blockIdx.x;
  int img = t >> 6, ty = (t>>3)&7, tx = t&7;
  int c0 = blockIdx.y*32;
  int tid = threadIdx.x;
  int ch = tid & 31;
  int c = c0 + ch;
  for (int v = tid; v < 3200; v += 256){
    int py = v / 160, rem = v - py*160;
    int px = rem >> 3, ch4 = (rem & 7)*4;
    int gpy = ty*16 - 2 + py, gpx = tx*16 - 2 + px;
    ushort4v val = {0,0,0,0};
    if ((unsigned)gpy < 128u && (unsigned)gpx < 128u){
      size_t gp = (size_t)(img*16384 + gpy*128 + gpx);
      val = *(const ushort4v*)&A3[gp*512 + c0 + ch4];
    }
    *(ushort4v*)&t0[(py*20+px)*32 + ch4] = val;
  }
  float w1[9], w2[9];
  #pragma unroll
  for (int k=0;k<9;k++){ w1[k] = w1g[k*256 + c]; w2[k] = w2g[k*256 + c]; }
  __syncthreads();
  for (int p = tid>>5; p < 324; p += 8){
    int py = p / 18, px = p - py*18;
    int gpy = ty*16 - 1 + py, gpx = tx*16 - 1 + px;
    float acc = 0.f;
    #pragma unroll
    for (int dy=0; dy<3; ++dy)
      #pragma unroll
      for (int dx=0; dx<3; ++dx)
        acc += bf2f(t0[((py+dy)*20 + px+dx)*32 + ch]) * w1[dy*3+dx];
    bool valid = ((unsigned)gpy < 128u) && ((unsigned)gpx < 128u);
    t1[p*32 + ch] = valid ? f2h(acc) : (unsigned short)0;
  }
  __syncthreads();
  float bmv = bm_[c];
  float rsbg = rsqrtf(bv[c] + 1e-3f) * bg[c];
  for (int p = tid>>5; p < 256; p += 8){
    int py = p >> 4, px = p & 15;
    float acc = 0.f;
    #pragma unroll
    for (int dy=0; dy<3; ++dy)
      #pragma unroll
      for (int dx=0; dx<3; ++dx)
        acc += h2f(t1[((py+dy)*18 + px+dx)*32 + ch]) * w2[dy*3+dx];
    float tv = (acc - bmv) * rsbg;
    float sv = tv / (1.f + __expf(-tv));
    size_t gp = (size_t)(img*16384 + (ty*16+py)*128 + tx*16+px);
    float z = sv - h2f(zdet[gp*256 + c]);
    zcx[gp*256 + c] = f2h(z);
  }
}

// ---------------- generic MFMA GEMM: C = A[M,K] * (Bt[N,K])^T, 128x128 tile, BK=64
template<int EPI>
__global__ __launch_bounds__(256) void k_gemm(const unsigned short* __restrict__ A, int lda,
                                              const unsigned short* __restrict__ Bt, int K,
                                              unsigned short* __restrict__ outh,
                                              const float* __restrict__ xin,
                                              const unsigned short* __restrict__ A3,
                                              const float* __restrict__ gls,
                                              float* __restrict__ out){
  __shared__ unsigned short As[128*64];
  __shared__ unsigned short Bs[128*64];
  const int tid=threadIdx.x, lane=tid&63, wid=tid>>6;
  const int bm = blockIdx.x*128, bn = blockIdx.y*128;
  const int wr = wid>>1, wc = wid&1;
  f32x4 acc[4][4] = {};
  const int nk = K>>6;
  const int srow = lane>>3;
  const int skc  = ((lane&7) ^ srow) * 8;
  for (int t=0; t<nk; ++t){
    int k0 = t*64;
    #pragma unroll
    for (int i=0;i<4;i++){
      int q = wid*4 + i;
      int row = q*8 + srow;
      gll16(A  + (size_t)(bm+row)*lda + k0 + skc, &As[q*512]);
      gll16(Bt + (size_t)(bn+row)*K   + k0 + skc, &Bs[q*512]);
    }
    __syncthreads();
    #pragma unroll
    for (int kk=0; kk<2; ++kk){
      bf16x8 af[4], bfr[4];
      #pragma unroll
      for (int i=0;i<4;i++){
        int rl = wr*64 + i*16 + (lane&15);
        int kc = (kk*32 + (lane>>4)*8) ^ ((rl&7)*8);
        af[i]  = *(const bf16x8*)&As[rl*64 + kc];
        int cl = wc*64 + i*16 + (lane&15);
        int kcb = (kk*32 + (lane>>4)*8) ^ ((cl&7)*8);
        bfr[i] = *(const bf16x8*)&Bs[cl*64 + kcb];
      }
      #pragma unroll
      for (int i=0;i<4;i++)
        #pragma unroll
        for (int j=0;j<4;j++)
          acc[i][j] = __builtin_amdgcn_mfma_f32_16x16x32_bf16(af[i], bfr[j], acc[i][j], 0,0,0);
    }
    __syncthreads();
  }
  #pragma unroll
  for (int i=0;i<4;i++)
    #pragma unroll
    for (int j=0;j<4;j++)
      #pragma unroll
      for (int r=0;r<4;r++){
        int row = bm + wr*64 + i*16 + (lane>>4)*4 + r;
        int col = bn + wc*64 + j*16 + (lane&15);
        float v = acc[i][j][r];
        if constexpr (EPI==0){
          outh[(size_t)row*256 + col] = f2h(v);   // z_det in FP16
        } else {
          float alpha = 1.f/(1.f+__expf(-v));
          float xnv = bf2f(A3[(size_t)row*512 + col]);
          float gfv = bf2f(A3[(size_t)row*512 + 256 + col]);
          float sl = xnv/(1.f+__expf(-xnv));
          out[(size_t)row*256 + col] = xin[(size_t)row*256 + col] + (sl + alpha*gfv)*gls[col];
        }
      }
}

// ---------------- fused geo GEMM: K=2816 (11 segs x 256), fp16 features
// Wave tile 64 rows x 64 cols (rg=4, fj=4): each LDS B-fragment reused 4x.
// LDS per buffer: [4 q][256 n][8 e] fp16 = 16KB, ring-4, stage-3-ahead, counted vmcnt.
template<int S>
__device__ __attribute__((always_inline)) ushort8 shsel(ushort8 hi, ushort8 lo){
  ushort8 r;
  if constexpr (S==0) return hi;
  #pragma unroll
  for (int e=0;e<8;e++) r[e] = (e<S) ? lo[8-S+e] : hi[e-S];
  return r;
}

template<int SEG>
__device__ __attribute__((always_inline)) f16x8 gen2(ushort8 zdh, ushort8 zdl,
      ushort8 zch, ushort8 zcl, ushort8 zcu){
  if constexpr (SEG==10) return __builtin_bit_cast(f16x8, zdh);
  ushort8 sel;
  if constexpr      (SEG==0) sel = shsel<1>(zch, zcl);
  else if constexpr (SEG==1) sel = shsel<7>(zcu, zch);
  else if constexpr (SEG==2) sel = shsel<2>(zch, zcl);
  else if constexpr (SEG==3) sel = shsel<6>(zcu, zch);
  else if constexpr (SEG==4) sel = shsel<4>(zch, zcl);
  else if constexpr (SEG==5) sel = shsel<4>(zcu, zch);
  else if constexpr (SEG==6) sel = zcl;
  else if constexpr (SEG==7) sel = zcu;
  else if constexpr (SEG==8) sel = shsel<1>(zdh, zdl);
  else                       sel = shsel<2>(zdh, zdl);
  return __builtin_bit_cast(f16x8, zdh) * __builtin_bit_cast(f16x8, sel);
}

__global__ __launch_bounds__(256, 2) void k_geo(const unsigned short* __restrict__ zd,
                                                const unsigned short* __restrict__ zc,
                                                const unsigned short* __restrict__ WT_all,
                                                const unsigned short* __restrict__ WeffT,
                                                unsigned short* __restrict__ A3){
  __shared__ unsigned short Bs[4][8192];     // ring-4 x 16KB, layout [q][n][8]
  const int tid = threadIdx.x, lane = tid&63, wid = tid>>6;
  const int bm = blockIdx.x*64;
  const int img = blockIdx.x >> 8;           // 256 blocks per image
  f32x4 acc[4][4] = {};                      // [rg][fj]

  // B-read offsets (ushorts): conflict-free by construction (16-lane linear runs)
  int boff[4];
  #pragma unroll
  for (int fj=0; fj<4; ++fj){
    int n = wid*64 + fj*16 + (lane&15);
    boff[fj] = (lane>>4)*2048 + n*8;
  }

  const int mrow = bm + (lane&15);
  const unsigned short* zr[4];
  const unsigned short* cr[4];
  #pragma unroll
  for (int rg=0; rg<4; ++rg){
    zr[rg] = zd + (size_t)(mrow + rg*16)*256;
    cr[rg] = zc + (size_t)(mrow + rg*16)*256;
  }

  ushort8 zdh[4], zdl[4], zch[4], zcl[4], zcu[4];
  int cur = 0;

#define STAGE(BUF, SP, KK) { \
    const unsigned short* src = (((SP)<10) ? (WT_all + (size_t)(SP)*65536) \
                                           : (WeffT + (size_t)img*65536)) \
                                + (size_t)(KK)*8192 + wid*2048 + lane*8; \
    gll16(src,        &Bs[BUF][wid*2048]); \
    gll16(src + 512,  &Bs[BUF][wid*2048 + 512]); \
    gll16(src + 1024, &Bs[BUF][wid*2048 + 1024]); \
    gll16(src + 1536, &Bs[BUF][wid*2048 + 1536]); \
  }

  STAGE(0, 0, 0)
  STAGE(1, 1, 0)
  STAGE(2, 2, 0)

#define STEP(P) { \
    if constexpr ((P)==1 || (P)==2){ asm volatile("s_waitcnt vmcnt(28)" ::: "memory"); } \
    else                           { asm volatile("s_waitcnt vmcnt(8)"  ::: "memory"); } \
    __builtin_amdgcn_s_barrier(); \
    if constexpr ((P)==0){ \
      int kc = k32*32 + (lane>>4)*8; \
      int kl = (kc-8)&255, ku = (kc+8)&255; \
      _Pragma("unroll") \
      for (int rg=0; rg<4; ++rg){ \
        zdh[rg] = *(const ushort8*)(zr[rg] + kc); \
        zdl[rg] = *(const ushort8*)(zr[rg] + kl); \
        zch[rg] = *(const ushort8*)(cr[rg] + kc); \
        zcl[rg] = *(const ushort8*)(cr[rg] + kl); \
        zcu[rg] = *(const ushort8*)(cr[rg] + ku); \
      } \
      __builtin_amdgcn_sched_barrier(0); \
    } \
    { constexpr int s3 = ((P)+3)%11; \
      int k3 = k32 + (((P)>=8) ? 1 : 0); if (k3 > 7) k3 = 7; \
      STAGE((cur+3)&3, s3, k3) } \
    f16x8 af[4]; \
    _Pragma("unroll") \
    for (int rg=0; rg<4; ++rg) af[rg] = gen2<(P)>(zdh[rg],zdl[rg],zch[rg],zcl[rg],zcu[rg]); \
    const unsigned short* bp = &Bs[cur][0]; \
    __builtin_amdgcn_s_setprio(1); \
    _Pragma("unroll") \
    for (int fj=0; fj<4; ++fj){ \
      f16x8 bfr = *(const f16x8*)&bp[boff[fj]]; \
      _Pragma("unroll") \
      for (int rg=0; rg<4; ++rg) \
        acc[rg][fj] = __builtin_amdgcn_mfma_f32_16x16x32_f16(af[rg], bfr, acc[rg][fj], 0,0,0); \
    } \
    __builtin_amdgcn_s_setprio(0); \
    cur = (cur+1)&3; \
  }

  for (int k32=0; k32<8; ++k32){
    STEP(0) STEP(1) STEP(2) STEP(3) STEP(4) STEP(5)
    STEP(6) STEP(7) STEP(8) STEP(9) STEP(10)
  }
#undef STEP
#undef STAGE

  #pragma unroll
  for (int rg=0; rg<4; ++rg)
    #pragma unroll
    for (int fj=0; fj<4; ++fj)
      #pragma unroll
      for (int r=0; r<4; ++r){
        int row = bm + rg*16 + (lane>>4)*4 + r;
        int col = wid*64 + fj*16 + (lane&15);
        A3[(size_t)row*512 + 256 + col] = f2bf(acc[rg][fj][r]);
      }
}

extern "C" void kernel_launch(void* const* d_in, const int* in_sizes, int n_in,
                              void* d_out, int out_size, void* d_ws, size_t ws_size,
                              hipStream_t stream){
  (void)in_sizes; (void)n_in; (void)out_size; (void)ws_size;
  const float* x    = (const float*)d_in[0];
  const float* lng  = (const float*)d_in[1];
  const float* wdet = (const float*)d_in[2];
  const float* dw1  = (const float*)d_in[3];
  const float* dw2  = (const float*)d_in[4];
  const float* bng  = (const float*)d_in[5];
  const float* bnm  = (const float*)d_in[6];
  const float* bnv  = (const float*)d_in[7];
  const float* wloc = (const float*)d_in[8];
  const float* wglo = (const float*)d_in[9];
  const float* wgat = (const float*)d_in[10];
  const float* gls  = (const float*)d_in[11];
  float* out = (float*)d_out;
  char* ws = (char*)d_ws;

  unsigned short* A3     = (unsigned short*)(ws);                 // 64 MB [65536][512] bf16
  unsigned short* ZDET   = (unsigned short*)(ws + 67108864);      // 32 MB fp16
  unsigned short* ZCX    = (unsigned short*)(ws + 134217728);     // 32 MB fp16
  unsigned short* WTALL  = (unsigned short*)(ws + 167772160);     // 1.25 MB fp16 [10][8][4][256][8]
  unsigned short* WEFFT  = (unsigned short*)(ws + 169213952);     // 0.5 MB fp16 [4][8][4][256][8]
  unsigned short* WDETT  = (unsigned short*)(ws + 169738240);     // 128 KB bf16
  unsigned short* WGATET = (unsigned short*)(ws + 169869312);     // 256 KB bf16
  float* PSUM  = (float*)(ws + 170131456);                        // 256 KB
  float* MMEAN = (float*)(ws + 170393600);                        // 4 KB

  k_ln<<<65536, 256, 0, stream>>>(x, lng, A3);
  k_cm1<<<256, 256, 0, stream>>>(A3, PSUM);
  k_cm2<<<4, 256, 0, stream>>>(PSUM, MMEAN);
  k_prep_nt<<<256, 256, 0, stream>>>(wdet, WDETT, 256);
  k_prep_nt<<<512, 256, 0, stream>>>(wgat, WGATET, 512);
  k_prep_geoT<<<2560, 256, 0, stream>>>(wloc, wglo, WTALL);
  k_prep_weff<<<1024, 256, 0, stream>>>(wglo, MMEAN, WEFFT);
  k_gemm<0><<<dim3(512,2), 256, 0, stream>>>(A3, 512, WDETT, 256, ZDET,
                                             nullptr, nullptr, nullptr, nullptr);
  k_dwf<<<dim3(256,8), 256, 0, stream>>>(A3, dw1, dw2, bng, bnm, bnv, ZDET, ZCX);
  k_geo<<<1024, 256, 0, stream>>>(ZDET, ZCX, WTALL, WEFFT, A3);
  k_gemm<1><<<dim3(512,2), 256, 0, stream>>>(A3, 512, WGATET, 512, nullptr,
                                             x, A3, gls, out);
}